// Round 9
// baseline (190.273 us; speedup 1.0000x reference)
//
#include <hip/hip_runtime.h>

#define NL 128          // N_LABELS
#define TT 512          // T
#define NB 512          // B
#define START_IDX 126
#define STOP_IDX 127

typedef __attribute__((ext_vector_type(8))) short bf16x8;
typedef __attribute__((ext_vector_type(4))) float f32x4;
typedef __attribute__((ext_vector_type(4))) unsigned u32x4;

__device__ __forceinline__ short f2bf(float x) {
    union { float f; unsigned u; } v; v.f = x;
    unsigned r = (v.u + 0x7FFFu + ((v.u >> 16) & 1u)) >> 16;  // RNE
    return (short)r;
}

__device__ __forceinline__ unsigned cvt_pk_bf16(float lo, float hi) {
    unsigned r;
    asm("v_cvt_pk_bf16_f32 %0, %1, %2" : "=v"(r) : "v"(lo), "v"(hi));
    return r;   // low half <- lo, high half <- hi
}

// LDS-only barrier: drain LDS ops (ds_write visibility) but NOT vmcnt — the
// in-flight global logits prefetches are lane-private.
#define BAR() do {                                                            \
    asm volatile("s_waitcnt lgkmcnt(0)" ::: "memory");                        \
    __builtin_amdgcn_s_barrier();                                             \
} while (0)

#define MFMA16(A_, B_, C_) __builtin_amdgcn_mfma_f32_16x16x32_bf16(A_, B_, C_, 0, 0, 0)

// ---------------------------------------------------------------------------
// One block = 16 batches (MFMA columns). 4 waves; wave w owns m-tiles {w, w+4}.
//   A[R][K] = exp(trans[R][phi(K)]), phi(kk*32+8g+j) = (kk+4*(j>>2))*16+4g+(j&3)
//   B[K][c] = v_c[phi(K)] ; C[R][c] = u_c[R], R = m*16+4g+reg.
// phi makes wave w's two C-frags exactly B-word-group kk=w (same lane):
// exchange = 1x ds_write_b128 + 3x ds_read_b128 / step, one barrier.
// Chain-shortening (R9): depth-2 MFMA partials (p: bO,bB / q: bA,bC, summed),
// exp block placed in the ds_read latency shadow, t+2 loads issued while the
// MFMA queue drains. Lag-1 cross-wave max (pub t%4==2, cons t%4==3) -> exact
// 2^k rescale. Per-batch freeze at t==lenc via keep-old cndmask.
// ---------------------------------------------------------------------------
#define STEP(T_, PUB_, CONS_, EC_, EO_, RC_, RO_) do {                        \
    u32x4 bo_ = {bw0, bw1, bw2, bw3};                                         \
    bf16x8 bO_ = __builtin_bit_cast(bf16x8, bo_);                             \
    bf16x8 bA_ = __builtin_bit_cast(bf16x8, bvA);                             \
    bf16x8 bB_ = __builtin_bit_cast(bf16x8, bvB);                             \
    bf16x8 bC_ = __builtin_bit_cast(bf16x8, bvC);                             \
    f32x4 p0_ = {0.f,0.f,0.f,0.f}, p1_ = {0.f,0.f,0.f,0.f};                   \
    f32x4 q0_ = {0.f,0.f,0.f,0.f}, q1_ = {0.f,0.f,0.f,0.f};                   \
    p0_ = MFMA16(afr[0][0], bO_, p0_);      /* own group, no LDS wait */      \
    p1_ = MFMA16(afr[1][0], bO_, p1_);                                        \
    _Pragma("unroll")                       /* exp in the ds_read shadow */   \
    for (int r_ = 0; r_ < 4; ++r_) {                                          \
        EO_##0[r_] = __expf(RO_##0[r_]);                                      \
        EO_##1[r_] = __expf(RO_##1[r_]);                                      \
    }                                                                         \
    q0_ = MFMA16(afr[0][1], bA_, q0_);                                        \
    q1_ = MFMA16(afr[1][1], bA_, q1_);                                        \
    p0_ = MFMA16(afr[0][2], bB_, p0_);                                        \
    p1_ = MFMA16(afr[1][2], bB_, p1_);                                        \
    q0_ = MFMA16(afr[0][3], bC_, q0_);                                        \
    q1_ = MFMA16(afr[1][3], bC_, q1_);                                        \
    { int tp_ = (T_) + 2; if (tp_ > TT - 1) tp_ = TT - 1;                     \
      const float* lp_ = lsrc + (size_t)tp_ * NL;                             \
      RC_##0 = *(const f32x4*)(lp_ + eo0);                                    \
      RC_##1 = *(const f32x4*)(lp_ + eo1); }                                  \
    f32x4 a0_ = p0_ + q0_;                                                    \
    f32x4 a1_ = p1_ + q1_;                                                    \
    float nv0_[4], nv1_[4];                                                   \
    _Pragma("unroll")                                                         \
    for (int r_ = 0; r_ < 4; ++r_) {                                          \
        nv0_[r_] = a0_[r_] * EC_##0[r_];                                      \
        nv1_[r_] = a1_[r_] * EC_##1[r_];                                      \
    }                                                                         \
    const bool live_ = (T_) < lenc;                                           \
    if (CONS_) {                                                              \
        float mx_ = fmaxf(fmaxf(smax[0][c], smax[1][c]),                      \
                          fmaxf(smax[2][c], smax[3][c]));                     \
        const unsigned eb_ = (__float_as_uint(mx_) >> 23) & 0xFFu;            \
        const float sc_ = __uint_as_float(((253u - eb_) & 0xFFu) << 23);      \
        _Pragma("unroll")                                                     \
        for (int r_ = 0; r_ < 4; ++r_) { nv0_[r_] *= sc_; nv1_[r_] *= sc_; }  \
        if (live_) cbi += (int)eb_ - 126;                                     \
    }                                                                         \
    if (PUB_) {                                                               \
        float lm_ = fmaxf(fmaxf(fmaxf(nv0_[0], nv0_[1]), fmaxf(nv0_[2], nv0_[3])), \
                          fmaxf(fmaxf(nv1_[0], nv1_[1]), fmaxf(nv1_[2], nv1_[3]))); \
        lm_ = fmaxf(lm_, __shfl_xor(lm_, 16));                                \
        lm_ = fmaxf(lm_, __shfl_xor(lm_, 32));                                \
        if (g == 0) smax[w][c] = lm_;                                         \
    }                                                                         \
    { const unsigned n0_ = cvt_pk_bf16(nv0_[0], nv0_[1]);                     \
      const unsigned n1_ = cvt_pk_bf16(nv0_[2], nv0_[3]);                     \
      const unsigned n2_ = cvt_pk_bf16(nv1_[0], nv1_[1]);                     \
      const unsigned n3_ = cvt_pk_bf16(nv1_[2], nv1_[3]);                     \
      bw0 = live_ ? n0_ : bw0;  bw1 = live_ ? n1_ : bw1;                      \
      bw2 = live_ ? n2_ : bw2;  bw3 = live_ ? n3_ : bw3; }                    \
    char* nb_ = sb[((T_) + 1) & 1];                                           \
    { u32x4 wv_ = {bw0, bw1, bw2, bw3};                                       \
      *(u32x4*)(nb_ + w * 1280 + slotOff) = wv_; }                            \
    BAR();                                                                    \
    bvA = *(const u32x4*)(nb_ + kA + slotOff);                                \
    bvB = *(const u32x4*)(nb_ + kB + slotOff);                                \
    bvC = *(const u32x4*)(nb_ + kC + slotOff);                                \
} while (0)

__global__ __launch_bounds__(256)
void crf_scan(const float* __restrict__ logits,
              const int* __restrict__ lens,
              const float* __restrict__ trans,
              float* __restrict__ out)
{
    const int b0   = blockIdx.x * 16;
    const int tid  = threadIdx.x;
    const int w    = tid >> 6;           // wave: owns m-tiles {w, w+4} = group kk=w
    const int lane = tid & 63;
    const int c    = lane & 15;          // batch / A row within tile / C col
    const int g    = lane >> 4;          // k-group

    // slot(kk,c,g) = kk*1280 + c*80 + g*16 (stride 80 -> conflict-light b128)
    __shared__ __align__(16) char sb[2][4 * 16 * 80];
    __shared__ float smax[4][16];

    // ---- A fragments, chain-ordered: pos -> logical kk = (w+pos)&3 ----
    bf16x8 afr[2][4];
    #pragma unroll
    for (int mi = 0; mi < 2; ++mi) {
        const int M = w + 4 * mi;
        const float* rowp = trans + (M * 16 + c) * NL + 4 * g;
        #pragma unroll
        for (int pos = 0; pos < 4; ++pos) {
            const int kk = (w + pos) & 3;
            f32x4 lo4 = *(const f32x4*)(rowp + kk * 16);        // e=0..3
            f32x4 hi4 = *(const f32x4*)(rowp + (kk + 4) * 16);  // e=4..7
            bf16x8 a;
            #pragma unroll
            for (int j = 0; j < 4; ++j) {
                a[j]     = f2bf(__expf(lo4[j]));
                a[j + 4] = f2bf(__expf(hi4[j]));
            }
            afr[mi][pos] = a;
        }
    }

    int lenc = lens[b0 + c];
    lenc = lenc < 1 ? 1 : (lenc > TT ? TT : lenc);
    int gl = lenc;
    #pragma unroll
    for (int d = 1; d < 16; d <<= 1) { int o = __shfl_xor(gl, d); gl = gl > o ? gl : o; }
    const int glen = __builtin_amdgcn_readfirstlane(gl);

    const int slotOff = c * 80 + g * 16;
    const int kA = ((w + 1) & 3) * 1280;
    const int kB = ((w + 2) & 3) * 1280;
    const int kC = ((w + 3) & 3) * 1280;

    // ---- init: v0 one-hot at START(126) -> group kk=3, g=3, word 3, low half
    unsigned bw0 = 0u, bw1 = 0u, bw2 = 0u,
             bw3 = (w == 3 && g == 3) ? 0x00003F80u : 0u;
    { u32x4 z = {bw0, bw1, bw2, bw3};
      *(u32x4*)(sb[0] + w * 1280 + slotOff) = z; }
    BAR();
    u32x4 bvA = *(const u32x4*)(sb[0] + kA + slotOff);
    u32x4 bvB = *(const u32x4*)(sb[0] + kB + slotOff);
    u32x4 bvC = *(const u32x4*)(sb[0] + kC + slotOff);

    const float* lsrc = logits + (size_t)(b0 + c) * TT * NL;
    const int eo0 = w * 16 + 4 * g;          // labels of m-tile w
    const int eo1 = (w + 4) * 16 + 4 * g;    // labels of m-tile w+4

    // el pipeline: raw loaded 2 steps ahead, exp'd 1 step ahead
    f32x4 R00, R01, R10, R11, E00, E01, E10, E11;
    R00 = *(const f32x4*)(lsrc + eo0);            R01 = *(const f32x4*)(lsrc + eo1);
    R10 = *(const f32x4*)(lsrc + NL + eo0);       R11 = *(const f32x4*)(lsrc + NL + eo1);
    #pragma unroll
    for (int r = 0; r < 4; ++r) {
        E00[r] = __expf(R00[r]); E01[r] = __expf(R01[r]);
        E10[r] = __expf(R10[r]); E11[r] = __expf(R11[r]);
    }

    int cbi = 0;
    int t = 0;
    for (; t + 4 <= glen; t += 4) {
        STEP(t + 0, false, false, E0, E1, R0, R1);
        STEP(t + 1, false, false, E1, E0, R1, R0);
        STEP(t + 2, true,  false, E0, E1, R0, R1);
        STEP(t + 3, false, true,  E1, E0, R1, R0);
    }
    for (; t < glen; ++t) {
        const bool pub = (t & 3) == 2, cons = (t & 3) == 3;
        if (t & 1) STEP(t, pub, cons, E1, E0, R1, R0);
        else       STEP(t, pub, cons, E0, E1, R0, R1);
    }

    // ---- epilogue (wave 0): final B-groups are bw(kk=0) + bvA/bvB/bvC (1,2,3)
    if (w == 0) {
        float s = 0.f;
        const float* stopr = trans + STOP_IDX * NL + 4 * g;
        u32x4 grp[4];
        grp[0] = (u32x4){bw0, bw1, bw2, bw3};
        grp[1] = bvA; grp[2] = bvB; grp[3] = bvC;
        #pragma unroll
        for (int kk = 0; kk < 4; ++kk) {
            f32x4 t0 = *(const f32x4*)(stopr + kk * 16);
            f32x4 t1 = *(const f32x4*)(stopr + (kk + 4) * 16);
            #pragma unroll
            for (int i = 0; i < 2; ++i) {
                const unsigned wd = grp[kk][i];
                s += __uint_as_float(wd << 16)         * __expf(t0[2 * i]);
                s += __uint_as_float(wd & 0xFFFF0000u) * __expf(t0[2 * i + 1]);
            }
            #pragma unroll
            for (int i = 2; i < 4; ++i) {
                const unsigned wd = grp[kk][i];
                s += __uint_as_float(wd << 16)         * __expf(t1[2 * (i - 2)]);
                s += __uint_as_float(wd & 0xFFFF0000u) * __expf(t1[2 * (i - 2) + 1]);
            }
        }
        s += __shfl_xor(s, 16);
        s += __shfl_xor(s, 32);
        if (g == 0)
            out[b0 + c] = (float)cbi * 0.69314718055994531f + __logf(s);
    }
}

extern "C" void kernel_launch(void* const* d_in, const int* in_sizes, int n_in,
                              void* d_out, int out_size, void* d_ws, size_t ws_size,
                              hipStream_t stream) {
    const float* logits = (const float*)d_in[0];
    const int*   lens   = (const int*)d_in[1];
    const float* trans  = (const float*)d_in[2];
    float*       outp   = (float*)d_out;
    crf_scan<<<NB / 16, 256, 0, stream>>>(logits, lens, trans, outp);
}

// Round 10
// 150.622 us; speedup vs baseline: 1.2633x; 1.2633x over previous
//
#include <hip/hip_runtime.h>

#define NL 128          // N_LABELS
#define TT 512          // T
#define NB 512          // B
#define START_IDX 126
#define STOP_IDX 127

typedef __attribute__((ext_vector_type(8))) short bf16x8;
typedef __attribute__((ext_vector_type(4))) float f32x4;
typedef __attribute__((ext_vector_type(4))) unsigned u32x4;

__device__ __forceinline__ short f2bf(float x) {
    union { float f; unsigned u; } v; v.f = x;
    unsigned r = (v.u + 0x7FFFu + ((v.u >> 16) & 1u)) >> 16;  // RNE
    return (short)r;
}

__device__ __forceinline__ unsigned cvt_pk_bf16(float lo, float hi) {
    unsigned r;
    asm("v_cvt_pk_bf16_f32 %0, %1, %2" : "=v"(r) : "v"(lo), "v"(hi));
    return r;   // low half <- lo, high half <- hi
}

// LDS-only barrier: drain LDS ops (ds_write visibility) but NOT vmcnt — the
// in-flight global logits prefetches are lane-private and must be allowed to
// span barriers (this is what makes the 2-step-deep el pipeline work).
#define BAR() do {                                                            \
    asm volatile("s_waitcnt lgkmcnt(0)" ::: "memory");                        \
    __builtin_amdgcn_s_barrier();                                             \
} while (0)

#define MFMA16(A_, B_, C_) __builtin_amdgcn_mfma_f32_16x16x32_bf16(A_, B_, C_, 0, 0, 0)

// ---------------------------------------------------------------------------
// One block = 16 batches (MFMA columns). 4 waves; wave w owns m-tiles {w, w+4}.
//   A[R][K] = exp(trans[R][phi(K)]), phi(kk*32+8g+j) = (kk+4*(j>>2))*16+4g+(j&3)
//   B[K][c] = v_c[phi(K)] ; C[R][c] = u_c[R], R = m*16+4g+reg.
// phi makes wave w's two C-frags exactly B-word-group kk=w (same lane):
// exchange = 1x ds_write_b128 + 3x ds_read_b128 / step, one LDS-only barrier.
// el pipeline (R10): 4 rotating raw pairs + 2 exp pairs. At step t:
//   use E(t) [built at t-1], build E(t+1) from raw(t+1) [ISSUED AT t-2 ->
//   ~1700cy cover > ~900cy HBM latency], issue raw(t+3).
// Lag-1 cross-wave max (pub t%4==2, cons t%4==3) -> exact 2^k rescale.
// Per-batch freeze at t==lenc via keep-old cndmask.
// ---------------------------------------------------------------------------
#define STEP(T_, PUB_, CONS_, EU_, EB_, RS_, RD_) do {                        \
    u32x4 bo_ = {bw0, bw1, bw2, bw3};                                         \
    bf16x8 bO_ = __builtin_bit_cast(bf16x8, bo_);                             \
    bf16x8 bA_ = __builtin_bit_cast(bf16x8, bvA);                             \
    bf16x8 bB_ = __builtin_bit_cast(bf16x8, bvB);                             \
    bf16x8 bC_ = __builtin_bit_cast(bf16x8, bvC);                             \
    f32x4 a0_ = {0.f,0.f,0.f,0.f}, a1_ = {0.f,0.f,0.f,0.f};                   \
    a0_ = MFMA16(afr[0][0], bO_, a0_);                                        \
    a1_ = MFMA16(afr[1][0], bO_, a1_);                                        \
    a0_ = MFMA16(afr[0][1], bA_, a0_);                                        \
    a1_ = MFMA16(afr[1][1], bA_, a1_);                                        \
    a0_ = MFMA16(afr[0][2], bB_, a0_);                                        \
    a1_ = MFMA16(afr[1][2], bB_, a1_);                                        \
    a0_ = MFMA16(afr[0][3], bC_, a0_);                                        \
    a1_ = MFMA16(afr[1][3], bC_, a1_);                                        \
    { int tp_ = (T_) + 3; if (tp_ > TT - 1) tp_ = TT - 1;                     \
      const float* lp_ = lsrc + (size_t)tp_ * NL;                             \
      RD_##A = *(const f32x4*)(lp_ + eo0);                                    \
      RD_##B = *(const f32x4*)(lp_ + eo1); }                                  \
    _Pragma("unroll")                                                         \
    for (int r_ = 0; r_ < 4; ++r_) {                                          \
        EB_##A[r_] = __expf(RS_##A[r_]);                                      \
        EB_##B[r_] = __expf(RS_##B[r_]);                                      \
    }                                                                         \
    float nv0_[4], nv1_[4];                                                   \
    _Pragma("unroll")                                                         \
    for (int r_ = 0; r_ < 4; ++r_) {                                          \
        nv0_[r_] = a0_[r_] * EU_##A[r_];                                      \
        nv1_[r_] = a1_[r_] * EU_##B[r_];                                      \
    }                                                                         \
    const bool live_ = (T_) < lenc;                                           \
    if (CONS_) {                                                              \
        float mx_ = fmaxf(fmaxf(smax[0][c], smax[1][c]),                      \
                          fmaxf(smax[2][c], smax[3][c]));                     \
        const unsigned eb_ = (__float_as_uint(mx_) >> 23) & 0xFFu;            \
        const float sc_ = __uint_as_float(((253u - eb_) & 0xFFu) << 23);      \
        _Pragma("unroll")                                                     \
        for (int r_ = 0; r_ < 4; ++r_) { nv0_[r_] *= sc_; nv1_[r_] *= sc_; }  \
        if (live_) cbi += (int)eb_ - 126;                                     \
    }                                                                         \
    if (PUB_) {                                                               \
        float lm_ = fmaxf(fmaxf(fmaxf(nv0_[0], nv0_[1]), fmaxf(nv0_[2], nv0_[3])), \
                          fmaxf(fmaxf(nv1_[0], nv1_[1]), fmaxf(nv1_[2], nv1_[3]))); \
        lm_ = fmaxf(lm_, __shfl_xor(lm_, 16));                                \
        lm_ = fmaxf(lm_, __shfl_xor(lm_, 32));                                \
        if (g == 0) smax[w][c] = lm_;                                         \
    }                                                                         \
    { const unsigned n0_ = cvt_pk_bf16(nv0_[0], nv0_[1]);                     \
      const unsigned n1_ = cvt_pk_bf16(nv0_[2], nv0_[3]);                     \
      const unsigned n2_ = cvt_pk_bf16(nv1_[0], nv1_[1]);                     \
      const unsigned n3_ = cvt_pk_bf16(nv1_[2], nv1_[3]);                     \
      bw0 = live_ ? n0_ : bw0;  bw1 = live_ ? n1_ : bw1;                      \
      bw2 = live_ ? n2_ : bw2;  bw3 = live_ ? n3_ : bw3; }                    \
    char* nb_ = sb[((T_) + 1) & 1];                                           \
    { u32x4 wv_ = {bw0, bw1, bw2, bw3};                                       \
      *(u32x4*)(nb_ + w * 1280 + slotOff) = wv_; }                            \
    BAR();                                                                    \
    bvA = *(const u32x4*)(nb_ + kA + slotOff);                                \
    bvB = *(const u32x4*)(nb_ + kB + slotOff);                                \
    bvC = *(const u32x4*)(nb_ + kC + slotOff);                                \
} while (0)

__global__ __launch_bounds__(256)
void crf_scan(const float* __restrict__ logits,
              const int* __restrict__ lens,
              const float* __restrict__ trans,
              float* __restrict__ out)
{
    const int b0   = blockIdx.x * 16;
    const int tid  = threadIdx.x;
    const int w    = tid >> 6;           // wave: owns m-tiles {w, w+4} = group kk=w
    const int lane = tid & 63;
    const int c    = lane & 15;          // batch / A row within tile / C col
    const int g    = lane >> 4;          // k-group

    // slot(kk,c,g) = kk*1280 + c*80 + g*16 (stride 80 -> conflict-light b128)
    __shared__ __align__(16) char sb[2][4 * 16 * 80];
    __shared__ float smax[4][16];

    // ---- A fragments, chain-ordered: pos -> logical kk = (w+pos)&3 ----
    bf16x8 afr[2][4];
    #pragma unroll
    for (int mi = 0; mi < 2; ++mi) {
        const int M = w + 4 * mi;
        const float* rowp = trans + (M * 16 + c) * NL + 4 * g;
        #pragma unroll
        for (int pos = 0; pos < 4; ++pos) {
            const int kk = (w + pos) & 3;
            f32x4 lo4 = *(const f32x4*)(rowp + kk * 16);        // e=0..3
            f32x4 hi4 = *(const f32x4*)(rowp + (kk + 4) * 16);  // e=4..7
            bf16x8 a;
            #pragma unroll
            for (int j = 0; j < 4; ++j) {
                a[j]     = f2bf(__expf(lo4[j]));
                a[j + 4] = f2bf(__expf(hi4[j]));
            }
            afr[mi][pos] = a;
        }
    }

    int lenc = lens[b0 + c];
    lenc = lenc < 1 ? 1 : (lenc > TT ? TT : lenc);
    int gl = lenc;
    #pragma unroll
    for (int d = 1; d < 16; d <<= 1) { int o = __shfl_xor(gl, d); gl = gl > o ? gl : o; }
    const int glen = __builtin_amdgcn_readfirstlane(gl);

    const int slotOff = c * 80 + g * 16;
    const int kA = ((w + 1) & 3) * 1280;
    const int kB = ((w + 2) & 3) * 1280;
    const int kC = ((w + 3) & 3) * 1280;

    // ---- init: v0 one-hot at START(126) -> group kk=3, g=3, word 3, low half
    unsigned bw0 = 0u, bw1 = 0u, bw2 = 0u,
             bw3 = (w == 3 && g == 3) ? 0x00003F80u : 0u;
    { u32x4 z = {bw0, bw1, bw2, bw3};
      *(u32x4*)(sb[0] + w * 1280 + slotOff) = z; }
    BAR();
    u32x4 bvA = *(const u32x4*)(sb[0] + kA + slotOff);
    u32x4 bvB = *(const u32x4*)(sb[0] + kB + slotOff);
    u32x4 bvC = *(const u32x4*)(sb[0] + kC + slotOff);

    const float* lsrc = logits + (size_t)(b0 + c) * TT * NL;
    const int eo0 = w * 16 + 4 * g;          // labels of m-tile w
    const int eo1 = (w + 4) * 16 + 4 * g;    // labels of m-tile w+4

    // ---- el pipeline: 4 rotating raw pairs, 2 exp pairs ----
    f32x4 R0A, R0B, R1A, R1B, R2A, R2B, R3A, R3B;
    f32x4 E0A, E0B, E1A, E1B;
    R0A = *(const f32x4*)(lsrc + eo0);            R0B = *(const f32x4*)(lsrc + eo1);
    R1A = *(const f32x4*)(lsrc + NL + eo0);       R1B = *(const f32x4*)(lsrc + NL + eo1);
    R2A = *(const f32x4*)(lsrc + 2 * NL + eo0);   R2B = *(const f32x4*)(lsrc + 2 * NL + eo1);
    #pragma unroll
    for (int r = 0; r < 4; ++r) {
        E0A[r] = __expf(R0A[r]);  E0B[r] = __expf(R0B[r]);
    }

    int cbi = 0;
    int t = 0;
    const int tmain = glen & ~3;
    for (; t < tmain; t += 4) {
        STEP(t + 0, false, false, E0, E1, R1, R3);
        STEP(t + 1, false, false, E1, E0, R2, R0);
        STEP(t + 2, true,  false, E0, E1, R3, R1);
        STEP(t + 3, false, true,  E1, E0, R0, R2);
    }
    if (t < glen) { STEP(t, false, false, E0, E1, R1, R3); ++t; }
    if (t < glen) { STEP(t, false, false, E1, E0, R2, R0); ++t; }
    if (t < glen) { STEP(t, true,  false, E0, E1, R3, R1); ++t; }

    // ---- epilogue (wave 0): final B-groups are bw(kk=0) + bvA/bvB/bvC (1,2,3)
    if (w == 0) {
        float s = 0.f;
        const float* stopr = trans + STOP_IDX * NL + 4 * g;
        u32x4 grp[4];
        grp[0] = (u32x4){bw0, bw1, bw2, bw3};
        grp[1] = bvA; grp[2] = bvB; grp[3] = bvC;
        #pragma unroll
        for (int kk = 0; kk < 4; ++kk) {
            f32x4 t0 = *(const f32x4*)(stopr + kk * 16);
            f32x4 t1 = *(const f32x4*)(stopr + (kk + 4) * 16);
            #pragma unroll
            for (int i = 0; i < 2; ++i) {
                const unsigned wd = grp[kk][i];
                s += __uint_as_float(wd << 16)         * __expf(t0[2 * i]);
                s += __uint_as_float(wd & 0xFFFF0000u) * __expf(t0[2 * i + 1]);
            }
            #pragma unroll
            for (int i = 2; i < 4; ++i) {
                const unsigned wd = grp[kk][i];
                s += __uint_as_float(wd << 16)         * __expf(t1[2 * (i - 2)]);
                s += __uint_as_float(wd & 0xFFFF0000u) * __expf(t1[2 * (i - 2) + 1]);
            }
        }
        s += __shfl_xor(s, 16);
        s += __shfl_xor(s, 32);
        if (g == 0)
            out[b0 + c] = (float)cbi * 0.69314718055994531f + __logf(s);
    }
}

extern "C" void kernel_launch(void* const* d_in, const int* in_sizes, int n_in,
                              void* d_out, int out_size, void* d_ws, size_t ws_size,
                              hipStream_t stream) {
    const float* logits = (const float*)d_in[0];
    const int*   lens   = (const int*)d_in[1];
    const float* trans  = (const float*)d_in[2];
    float*       outp   = (float*)d_out;
    crf_scan<<<NB / 16, 256, 0, stream>>>(logits, lens, trans, outp);
}